// Round 1
// baseline (886.971 us; speedup 1.0000x reference)
//
#include <hip/hip_runtime.h>
#include <math.h>

// Problem constants (from reference)
#define KTOT  8192
#define WORD  32
#define TDIM  512
#define FRAME 12
#define VDIM  512
#define BATCH 8

#define KSPLIT 1024             // k-range splits (grid.x of score)
#define KPB    (KTOT / KSPLIT)  // 8 k's per block
#define KC     4                // k-chunk held in registers
#define DPT    2                // d's per thread (float2 loads, 8 B/lane)

// float -> order-preserving uint32 (for packed atomicMin argmin)
__device__ __forceinline__ unsigned int f32_sortable(float f) {
    unsigned int u = __float_as_uint(f);
    return (u & 0x80000000u) ? ~u : (u | 0x80000000u);
}

// Precompute log(query) into ws and init packed argmin cells to +inf.
__global__ __launch_bounds__(256) void prep_kernel(const float* __restrict__ query,
                                                   float* __restrict__ logq,
                                                   unsigned long long* __restrict__ packed) {
    int g = blockIdx.x * 256 + threadIdx.x;
    if (g < BATCH * WORD * TDIM) logq[g] = logf(query[g]);
    if (g < BATCH * TDIM) packed[g] = 0xFFFFFFFFFFFFFFFFULL;
}

// score[b,k,d] = sum_w qt*(log qt - log q); running argmin over this block's
// k-range, folded into global packed atomicMin.
// Thread owns TWO consecutive d's (float2 = 8 B/lane coalesced streaming of qt).
__global__ __launch_bounds__(256) void score_kernel(const float* __restrict__ qt,
                                                    const float* __restrict__ logq,
                                                    unsigned long long* __restrict__ packed) {
    const int d0 = threadIdx.x * DPT;      // 256 threads cover D=512
    const int k0 = blockIdx.x * KPB;

    float minval[BATCH][DPT];
    int   minidx[BATCH][DPT];
#pragma unroll
    for (int b = 0; b < BATCH; ++b)
#pragma unroll
        for (int dd = 0; dd < DPT; ++dd) { minval[b][dd] = INFINITY; minidx[b][dd] = 0; }

    for (int kc = 0; kc < KPB; kc += KC) {
        float selfa[KC][DPT];          // sum_w qt*log(qt)   (batch-independent)
        float cross[BATCH][KC][DPT];   // sum_w qt*log(q_b)
#pragma unroll
        for (int kk = 0; kk < KC; ++kk)
#pragma unroll
            for (int dd = 0; dd < DPT; ++dd) selfa[kk][dd] = 0.f;
#pragma unroll
        for (int b = 0; b < BATCH; ++b)
#pragma unroll
            for (int kk = 0; kk < KC; ++kk)
#pragma unroll
                for (int dd = 0; dd < DPT; ++dd) cross[b][kk][dd] = 0.f;

#pragma unroll 4
        for (int w = 0; w < WORD; ++w) {
            // 4 coalesced float2 qt loads (wave-uniform offsets + lane d-pair)
            float2 q[KC];
#pragma unroll
            for (int kk = 0; kk < KC; ++kk)
                q[kk] = *(const float2*)(qt + (size_t)(k0 + kc + kk) * (WORD * TDIM)
                                            + w * TDIM + d0);
            // 8 float2 logq loads, L2-resident (512 KB working set)
            float2 lq[BATCH];
#pragma unroll
            for (int b = 0; b < BATCH; ++b)
                lq[b] = *(const float2*)(logq + (b * WORD + w) * TDIM + d0);

#pragma unroll
            for (int kk = 0; kk < KC; ++kk) {
                selfa[kk][0] = fmaf(q[kk].x, logf(q[kk].x), selfa[kk][0]);
                selfa[kk][1] = fmaf(q[kk].y, logf(q[kk].y), selfa[kk][1]);
            }
#pragma unroll
            for (int b = 0; b < BATCH; ++b)
#pragma unroll
                for (int kk = 0; kk < KC; ++kk) {
                    cross[b][kk][0] = fmaf(q[kk].x, lq[b].x, cross[b][kk][0]);
                    cross[b][kk][1] = fmaf(q[kk].y, lq[b].y, cross[b][kk][1]);
                }
        }
        // strict < keeps the FIRST (lowest-k) minimum, matching jnp.argmin
#pragma unroll
        for (int b = 0; b < BATCH; ++b)
#pragma unroll
            for (int kk = 0; kk < KC; ++kk)
#pragma unroll
                for (int dd = 0; dd < DPT; ++dd) {
                    float s = selfa[kk][dd] - cross[b][kk][dd];
                    if (s < minval[b][dd]) { minval[b][dd] = s; minidx[b][dd] = k0 + kc + kk; }
                }
    }
    // packed = (sortable(score) << 32) | k  -> atomicMin gives global argmin
    // with lowest-k tie-break (== numpy first-min semantics).
#pragma unroll
    for (int b = 0; b < BATCH; ++b)
#pragma unroll
        for (int dd = 0; dd < DPT; ++dd) {
            unsigned long long p =
                ((unsigned long long)f32_sortable(minval[b][dd]) << 32)
              | (unsigned long long)(unsigned int)minidx[b][dd];
            atomicMin(&packed[b * TDIM + d0 + dd], p);
        }
}

// out[b,d,:,:] = queue_video[idx[b,d],:,:] ; one block per (b,d) cell,
// 6144 floats = 1536 float4 copied by 256 threads (6 each), fully coalesced.
__global__ __launch_bounds__(256) void gather_kernel(const float* __restrict__ qv,
                                                     const unsigned long long* __restrict__ packed,
                                                     float* __restrict__ out) {
    const int cell = blockIdx.x;   // b*TDIM + d
    const unsigned int k = (unsigned int)(packed[cell] & 0xFFFFFFFFULL);
    const float4* src = (const float4*)(qv  + (size_t)k    * (FRAME * VDIM));
    float4*       dst = (float4*)      (out + (size_t)cell * (FRAME * VDIM));
#pragma unroll
    for (int i = 0; i < (FRAME * VDIM / 4) / 256; ++i)
        dst[threadIdx.x + i * 256] = src[threadIdx.x + i * 256];
}

extern "C" void kernel_launch(void* const* d_in, const int* in_sizes, int n_in,
                              void* d_out, int out_size, void* d_ws, size_t ws_size,
                              hipStream_t stream) {
    const float* query       = (const float*)d_in[0];  // [8,32,512]
    const float* queue_text  = (const float*)d_in[1];  // [8192,32,512]
    const float* queue_video = (const float*)d_in[2];  // [8192,12,512]
    float* out = (float*)d_out;                        // [8,512,12,512]

    // workspace layout: [0,32KB) packed argmin cells ; [32KB, 32KB+512KB) logq
    unsigned long long* packed = (unsigned long long*)d_ws;
    float* logq = (float*)((char*)d_ws + 32768);

    prep_kernel<<<512, 256, 0, stream>>>(query, logq, packed);
    score_kernel<<<KSPLIT, 256, 0, stream>>>(queue_text, logq, packed);
    gather_kernel<<<BATCH * TDIM, 256, 0, stream>>>(queue_video, packed, out);
}